// Round 1
// baseline (256.748 us; speedup 1.0000x reference)
//
#include <hip/hip_runtime.h>

#define NN 4096
#define DD 256
#define MARGIN 0.5f
#define LDP 68   // 64 + 4 pad: keeps float4 LDS reads 16B-aligned, spreads banks

// ---------------------------------------------------------------------------
// Kernel A: per-row stats. n1[i]=||p1_i||^2, n2[i]=||p2_i||^2, ap[i]=||p1_i-p2_i||^2
// One block (256 threads) per row; D=256 -> one element per thread.
// ---------------------------------------------------------------------------
__global__ __launch_bounds__(256) void row_stats(
    const float* __restrict__ p1, const float* __restrict__ p2,
    float* __restrict__ n1, float* __restrict__ n2, float* __restrict__ ap)
{
    const int row = blockIdx.x;
    const int t = threadIdx.x;
    float x = p1[row * DD + t];
    float y = p2[row * DD + t];
    float s1 = x * x;
    float s2 = y * y;
    float d = x - y;
    float sa = d * d;
    // wave (64-lane) reduction
    #pragma unroll
    for (int off = 32; off > 0; off >>= 1) {
        s1 += __shfl_down(s1, off);
        s2 += __shfl_down(s2, off);
        sa += __shfl_down(sa, off);
    }
    __shared__ float w1[4], w2[4], wa[4];
    const int wave = t >> 6;
    if ((t & 63) == 0) { w1[wave] = s1; w2[wave] = s2; wa[wave] = sa; }
    __syncthreads();
    if (t == 0) {
        n1[row] = w1[0] + w1[1] + w1[2] + w1[3];
        n2[row] = w2[0] + w2[1] + w2[2] + w2[3];
        ap[row] = wa[0] + wa[1] + wa[2] + wa[3];
    }
}

// ---------------------------------------------------------------------------
// Kernel B: 64x64 (i,j) tiles. Computes dot1 = p1_i . p1_j and dot2 = p1_i . p2_j
// via LDS-staged K-chunks (BK=64), then the hinge epilogue and a block-level
// partial sum (deterministic: no float atomics).
// ---------------------------------------------------------------------------
__global__ __launch_bounds__(256) void pair_tile(
    const float* __restrict__ p1, const float* __restrict__ p2,
    const float* __restrict__ n1, const float* __restrict__ n2,
    const float* __restrict__ ap, float* __restrict__ partial)
{
    __shared__ float As [64 * LDP];
    __shared__ float B1s[64 * LDP];
    __shared__ float B2s[64 * LDP];
    __shared__ float wsum[4];

    const int t  = threadIdx.x;
    const int tx = t & 15;        // j micro-tile index (4 cols)
    const int ty = t >> 4;        // i micro-tile index (4 rows)
    const int i0 = blockIdx.y * 64;
    const int j0 = blockIdx.x * 64;

    float dot1[4][4];
    float dot2[4][4];
    #pragma unroll
    for (int m = 0; m < 4; ++m)
        #pragma unroll
        for (int n = 0; n < 4; ++n) { dot1[m][n] = 0.f; dot2[m][n] = 0.f; }

    for (int kc = 0; kc < DD; kc += 64) {
        // ---- stage 3 tiles, transposed to [k][row] in LDS ----
        #pragma unroll
        for (int it = t; it < 64 * 16; it += 256) {
            const int row = it >> 4;
            const int k4  = (it & 15) << 2;
            const float4 a  = *(const float4*)&p1[(size_t)(i0 + row) * DD + kc + k4];
            const float4 b1 = *(const float4*)&p1[(size_t)(j0 + row) * DD + kc + k4];
            const float4 b2 = *(const float4*)&p2[(size_t)(j0 + row) * DD + kc + k4];
            As [(k4 + 0) * LDP + row] = a.x;  As [(k4 + 1) * LDP + row] = a.y;
            As [(k4 + 2) * LDP + row] = a.z;  As [(k4 + 3) * LDP + row] = a.w;
            B1s[(k4 + 0) * LDP + row] = b1.x; B1s[(k4 + 1) * LDP + row] = b1.y;
            B1s[(k4 + 2) * LDP + row] = b1.z; B1s[(k4 + 3) * LDP + row] = b1.w;
            B2s[(k4 + 0) * LDP + row] = b2.x; B2s[(k4 + 1) * LDP + row] = b2.y;
            B2s[(k4 + 2) * LDP + row] = b2.z; B2s[(k4 + 3) * LDP + row] = b2.w;
        }
        __syncthreads();

        // ---- inner product over this K chunk ----
        #pragma unroll 8
        for (int k = 0; k < 64; ++k) {
            const float4 av  = *(const float4*)&As [k * LDP + ty * 4];
            const float4 b1v = *(const float4*)&B1s[k * LDP + tx * 4];
            const float4 b2v = *(const float4*)&B2s[k * LDP + tx * 4];
            const float am[4]  = { av.x,  av.y,  av.z,  av.w  };
            const float bn1[4] = { b1v.x, b1v.y, b1v.z, b1v.w };
            const float bn2[4] = { b2v.x, b2v.y, b2v.z, b2v.w };
            #pragma unroll
            for (int m = 0; m < 4; ++m)
                #pragma unroll
                for (int n = 0; n < 4; ++n) {
                    dot1[m][n] = fmaf(am[m], bn1[n], dot1[m][n]);
                    dot2[m][n] = fmaf(am[m], bn2[n], dot2[m][n]);
                }
        }
        __syncthreads();
    }

    // ---- hinge epilogue ----
    const int ibase = i0 + ty * 4;
    const int jbase = j0 + tx * 4;
    float n1i[4], api[4], n1j[4], n2j[4];
    #pragma unroll
    for (int m = 0; m < 4; ++m) { n1i[m] = n1[ibase + m]; api[m] = ap[ibase + m]; }
    #pragma unroll
    for (int n = 0; n < 4; ++n) { n1j[n] = n1[jbase + n]; n2j[n] = n2[jbase + n]; }

    float acc = 0.f;
    #pragma unroll
    for (int m = 0; m < 4; ++m) {
        #pragma unroll
        for (int n = 0; n < 4; ++n) {
            const int i = ibase + m, j = jbase + n;
            const float d11 = n1i[m] + n1j[n] - 2.f * dot1[m][n];
            const float d12 = n1i[m] + n2j[n] - 2.f * dot2[m][n];
            float h = fmaxf(api[m] - d11 + MARGIN, 0.f)
                    + fmaxf(api[m] - d12 + MARGIN, 0.f);
            if (i != j) acc += h;
        }
    }

    // ---- block reduction ----
    #pragma unroll
    for (int off = 32; off > 0; off >>= 1) acc += __shfl_down(acc, off);
    if ((t & 63) == 0) wsum[t >> 6] = acc;
    __syncthreads();
    if (t == 0)
        partial[blockIdx.y * gridDim.x + blockIdx.x] =
            wsum[0] + wsum[1] + wsum[2] + wsum[3];
}

// ---------------------------------------------------------------------------
// Kernel C: sum 4096 partials, scale, write scalar.
// ---------------------------------------------------------------------------
__global__ __launch_bounds__(256) void final_reduce(
    const float* __restrict__ partial, float* __restrict__ out,
    int n, float scale)
{
    const int t = threadIdx.x;
    float s = 0.f;
    for (int i = t; i < n; i += 256) s += partial[i];
    #pragma unroll
    for (int off = 32; off > 0; off >>= 1) s += __shfl_down(s, off);
    __shared__ float w[4];
    if ((t & 63) == 0) w[t >> 6] = s;
    __syncthreads();
    if (t == 0) out[0] = (w[0] + w[1] + w[2] + w[3]) * scale;
}

// ---------------------------------------------------------------------------
extern "C" void kernel_launch(void* const* d_in, const int* in_sizes, int n_in,
                              void* d_out, int out_size, void* d_ws, size_t ws_size,
                              hipStream_t stream) {
    const float* p1 = (const float*)d_in[0];
    const float* p2 = (const float*)d_in[1];
    float* out = (float*)d_out;

    float* w       = (float*)d_ws;
    float* n1      = w;               // [NN]
    float* n2      = w + NN;          // [NN]
    float* ap      = w + 2 * NN;      // [NN]
    float* partial = w + 3 * NN;      // [64*64]

    row_stats<<<NN, 256, 0, stream>>>(p1, p2, n1, n2, ap);
    pair_tile<<<dim3(64, 64), 256, 0, stream>>>(p1, p2, n1, n2, ap, partial);
    const float scale = 1.0f / ((float)NN * (float)(NN - 1));
    final_reduce<<<1, 256, 0, stream>>>(partial, out, 64 * 64, scale);
}

// Round 2
// 76.776 us; speedup vs baseline: 3.3441x; 3.3441x over previous
//
#include <hip/hip_runtime.h>

#define NN 4096
#define DD 256
#define MARGIN 0.5f

typedef __attribute__((ext_vector_type(8))) short bf16x8;  // 8 bf16 (4 VGPRs)
typedef __attribute__((ext_vector_type(4))) float f32x4;   // MFMA C/D

// ---------------------------------------------------------------------------
// Kernel A: fused per-row stats (fp32) + fp32->bf16 conversion.
// n1[i]=||p1_i||^2, n2[i]=||p2_i||^2, ap[i]=||p1_i-p2_i||^2 (exact fp32 diag).
// One block per row, one element per thread (D=256).
// ---------------------------------------------------------------------------
__device__ inline unsigned short f32_to_bf16_rne(float v) {
    unsigned int b = __float_as_uint(v);
    b += 0x7FFFu + ((b >> 16) & 1u);   // round-to-nearest-even
    return (unsigned short)(b >> 16);
}

__global__ __launch_bounds__(256) void stats_convert(
    const float* __restrict__ p1, const float* __restrict__ p2,
    unsigned short* __restrict__ p1b, unsigned short* __restrict__ p2b,
    float* __restrict__ n1, float* __restrict__ n2, float* __restrict__ ap)
{
    const int row = blockIdx.x;
    const int t = threadIdx.x;
    const size_t idx = (size_t)row * DD + t;
    const float x = p1[idx];
    const float y = p2[idx];
    p1b[idx] = f32_to_bf16_rne(x);
    p2b[idx] = f32_to_bf16_rne(y);

    float s1 = x * x;
    float s2 = y * y;
    const float d = x - y;
    float sa = d * d;
    #pragma unroll
    for (int off = 32; off > 0; off >>= 1) {
        s1 += __shfl_down(s1, off);
        s2 += __shfl_down(s2, off);
        sa += __shfl_down(sa, off);
    }
    __shared__ float w1[4], w2[4], wa[4];
    const int wave = t >> 6;
    if ((t & 63) == 0) { w1[wave] = s1; w2[wave] = s2; wa[wave] = sa; }
    __syncthreads();
    if (t == 0) {
        n1[row] = w1[0] + w1[1] + w1[2] + w1[3];
        n2[row] = w2[0] + w2[1] + w2[2] + w2[3];
        ap[row] = wa[0] + wa[1] + wa[2] + wa[3];
    }
}

// ---------------------------------------------------------------------------
// Kernel B: MFMA pair kernel. Block = 256 thr = 4 waves (2x2), block tile
// 128x128, wave tile 64x64 (4x4 frags of 16x16). Two accumulator sets:
// dot1 = p1_i . p1_j, dot2 = p1_i . p2_j. Fragments loaded directly from
// global (bf16 operands are L2-resident; no LDS, no barriers in main loop).
//
// A-frag (16x32): lane holds row = lane&15, k = (lane>>4)*8 + e (8 contiguous
// bf16 = one 16B load). B-frag mirrors with col = lane&15.
// C/D frag: col = lane&15, row = (lane>>4)*4 + reg  [measured m89/m91].
// ---------------------------------------------------------------------------
__global__ __launch_bounds__(256) void pair_mfma(
    const unsigned short* __restrict__ p1b, const unsigned short* __restrict__ p2b,
    const float* __restrict__ n1, const float* __restrict__ n2,
    const float* __restrict__ ap, float* __restrict__ partial)
{
    const int t    = threadIdx.x;
    const int lane = t & 63;
    const int wave = t >> 6;
    const int wm   = wave >> 1;
    const int wn   = wave & 1;
    const int i0   = blockIdx.y * 128 + wm * 64;
    const int j0   = blockIdx.x * 128 + wn * 64;

    const int lr = lane & 15;          // row (A) / col (B) within 16
    const int lk = (lane >> 4) * 8;    // k-offset of this lane's 8 elements

    f32x4 acc1[4][4];
    f32x4 acc2[4][4];
    #pragma unroll
    for (int m = 0; m < 4; ++m)
        #pragma unroll
        for (int n = 0; n < 4; ++n) {
            acc1[m][n] = (f32x4){0.f, 0.f, 0.f, 0.f};
            acc2[m][n] = (f32x4){0.f, 0.f, 0.f, 0.f};
        }

    const unsigned short* aB  = p1b + (size_t)(i0 + lr) * DD + lk;
    const unsigned short* b1B = p1b + (size_t)(j0 + lr) * DD + lk;
    const unsigned short* b2B = p2b + (size_t)(j0 + lr) * DD + lk;

    for (int kc = 0; kc < DD; kc += 32) {
        bf16x8 a[4], b1[4], b2[4];
        #pragma unroll
        for (int m = 0; m < 4; ++m)
            a[m] = *(const bf16x8*)(aB + (size_t)m * 16 * DD + kc);
        #pragma unroll
        for (int n = 0; n < 4; ++n) {
            b1[n] = *(const bf16x8*)(b1B + (size_t)n * 16 * DD + kc);
            b2[n] = *(const bf16x8*)(b2B + (size_t)n * 16 * DD + kc);
        }
        #pragma unroll
        for (int m = 0; m < 4; ++m)
            #pragma unroll
            for (int n = 0; n < 4; ++n) {
                acc1[m][n] = __builtin_amdgcn_mfma_f32_16x16x32_bf16(
                    a[m], b1[n], acc1[m][n], 0, 0, 0);
                acc2[m][n] = __builtin_amdgcn_mfma_f32_16x16x32_bf16(
                    a[m], b2[n], acc2[m][n], 0, 0, 0);
            }
    }

    // ---- hinge epilogue (fp32) ----
    const int cj = lane & 15;
    const int r0 = (lane >> 4) * 4;
    float lsum = 0.f;
    #pragma unroll
    for (int m = 0; m < 4; ++m) {
        const int ib = i0 + m * 16 + r0;
        float api[4], n1i[4];
        #pragma unroll
        for (int r = 0; r < 4; ++r) { api[r] = ap[ib + r]; n1i[r] = n1[ib + r]; }
        #pragma unroll
        for (int n = 0; n < 4; ++n) {
            const int j = j0 + n * 16 + cj;
            const float n1j = n1[j];
            const float n2j = n2[j];
            #pragma unroll
            for (int r = 0; r < 4; ++r) {
                const int i = ib + r;
                const float d11 = n1i[r] + n1j - 2.f * acc1[m][n][r];
                const float d12 = n1i[r] + n2j - 2.f * acc2[m][n][r];
                float h = fmaxf(api[r] - d11 + MARGIN, 0.f)
                        + fmaxf(api[r] - d12 + MARGIN, 0.f);
                if (i != j) lsum += h;
            }
        }
    }

    // ---- block reduction (deterministic) ----
    #pragma unroll
    for (int off = 32; off > 0; off >>= 1) lsum += __shfl_down(lsum, off);
    __shared__ float wsum[4];
    if ((t & 63) == 0) wsum[wave] = lsum;
    __syncthreads();
    if (t == 0)
        partial[blockIdx.y * gridDim.x + blockIdx.x] =
            wsum[0] + wsum[1] + wsum[2] + wsum[3];
}

// ---------------------------------------------------------------------------
// Kernel C: sum partials, scale, write scalar.
// ---------------------------------------------------------------------------
__global__ __launch_bounds__(256) void final_reduce(
    const float* __restrict__ partial, float* __restrict__ out,
    int n, float scale)
{
    const int t = threadIdx.x;
    float s = 0.f;
    for (int i = t; i < n; i += 256) s += partial[i];
    #pragma unroll
    for (int off = 32; off > 0; off >>= 1) s += __shfl_down(s, off);
    __shared__ float w[4];
    if ((t & 63) == 0) w[t >> 6] = s;
    __syncthreads();
    if (t == 0) out[0] = (w[0] + w[1] + w[2] + w[3]) * scale;
}

// ---------------------------------------------------------------------------
extern "C" void kernel_launch(void* const* d_in, const int* in_sizes, int n_in,
                              void* d_out, int out_size, void* d_ws, size_t ws_size,
                              hipStream_t stream) {
    const float* p1 = (const float*)d_in[0];
    const float* p2 = (const float*)d_in[1];
    float* out = (float*)d_out;

    char* ws = (char*)d_ws;
    unsigned short* p1b = (unsigned short*)ws;                       // 2 MB
    unsigned short* p2b = (unsigned short*)(ws + (size_t)NN * DD * 2);   // 2 MB
    float* n1      = (float*)(ws + (size_t)NN * DD * 4);             // 16 KB
    float* n2      = n1 + NN;
    float* ap      = n2 + NN;
    float* partial = ap + NN;                                        // 1024 f32

    stats_convert<<<NN, 256, 0, stream>>>(p1, p2, p1b, p2b, n1, n2, ap);
    pair_mfma<<<dim3(32, 32), 256, 0, stream>>>(p1b, p2b, n1, n2, ap, partial);
    const float scale = 1.0f / ((float)NN * (float)(NN - 1));
    final_reduce<<<1, 256, 0, stream>>>(partial, out, 32 * 32, scale);
}

// Round 3
// 42.649 us; speedup vs baseline: 6.0200x; 1.8002x over previous
//
#include <hip/hip_runtime.h>

#define NN 4096
#define DD 256
#define MARGIN 0.5f

typedef __attribute__((ext_vector_type(8))) short bf16x8;  // 8 bf16 (4 VGPRs)
typedef __attribute__((ext_vector_type(4))) float f32x4;   // MFMA C/D

__device__ inline unsigned short f32_to_bf16_rne(float v) {
    unsigned int b = __float_as_uint(v);
    b += 0x7FFFu + ((b >> 16) & 1u);   // round-to-nearest-even
    return (unsigned short)(b >> 16);
}

// ---------------------------------------------------------------------------
// Kernel A: per-row stats + bf16 convert into concatenated layout.
// pb rows [0,4096) = p1, rows [4096,8192) = p2.  nb[j] = ||row_j||^2 (fp32).
// ai[i] = ||p1_i - p2_i||^2 - ||p1_i||^2 + MARGIN   (exact fp32).
// One wave per row; lane handles 4 elements via float4.
// ---------------------------------------------------------------------------
__global__ __launch_bounds__(256) void stats_convert(
    const float* __restrict__ p1, const float* __restrict__ p2,
    unsigned short* __restrict__ pb, float* __restrict__ nb,
    float* __restrict__ ai)
{
    const int wave = threadIdx.x >> 6;
    const int lane = threadIdx.x & 63;
    const int row  = blockIdx.x * 4 + wave;

    const float4 x = *(const float4*)&p1[(size_t)row * DD + lane * 4];
    const float4 y = *(const float4*)&p2[(size_t)row * DD + lane * 4];

    ushort4 xb, yb;
    xb.x = f32_to_bf16_rne(x.x); xb.y = f32_to_bf16_rne(x.y);
    xb.z = f32_to_bf16_rne(x.z); xb.w = f32_to_bf16_rne(x.w);
    yb.x = f32_to_bf16_rne(y.x); yb.y = f32_to_bf16_rne(y.y);
    yb.z = f32_to_bf16_rne(y.z); yb.w = f32_to_bf16_rne(y.w);
    *(ushort4*)&pb[(size_t)row * DD + lane * 4] = xb;
    *(ushort4*)&pb[(size_t)(NN + row) * DD + lane * 4] = yb;

    float s1 = x.x*x.x + x.y*x.y + x.z*x.z + x.w*x.w;
    float s2 = y.x*y.x + y.y*y.y + y.z*y.z + y.w*y.w;
    float dx = x.x-y.x, dy = x.y-y.y, dz = x.z-y.z, dw = x.w-y.w;
    float sa = dx*dx + dy*dy + dz*dz + dw*dw;

    #pragma unroll
    for (int off = 32; off > 0; off >>= 1) {
        s1 += __shfl_down(s1, off);
        s2 += __shfl_down(s2, off);
        sa += __shfl_down(sa, off);
    }
    if (lane == 0) {
        nb[row]      = s1;
        nb[NN + row] = s2;
        ai[row]      = sa - s1 + MARGIN;
    }
}

// ---------------------------------------------------------------------------
// Kernel B: bf16 GEMM (M=4096 x N=8192 x K=256) with fused hinge epilogue.
// Block tile 128x128, BK=64, 256 thr = 4 waves (2x2), wave tile 64x64
// (4x4 frags of 16x16x32). Double-buffered LDS staged via global_load_lds
// width=16 (linear dest, per T3 minimum 2-phase recipe).
// Epilogue: h = relu(ai[i] - nb[j] + 2*dot), skip j==i and j==i+NN.
// ---------------------------------------------------------------------------
__global__ __launch_bounds__(256) void gemm_hinge(
    const unsigned short* __restrict__ pb,
    const float* __restrict__ nb, const float* __restrict__ ai,
    float* __restrict__ partial)
{
    __shared__ unsigned short As[2][128 * 64];
    __shared__ unsigned short Bs[2][128 * 64];
    __shared__ float wsum[4];

    const int t    = threadIdx.x;
    const int lane = t & 63;
    const int wave = t >> 6;
    const int wm   = wave >> 1;
    const int wn   = wave & 1;
    const int i0   = blockIdx.y * 128;   // 0..3968  (A = p1 rows)
    const int j0   = blockIdx.x * 128;   // 0..8064  (B = concat rows)

    const int lr = lane & 15;
    const int lk = (lane >> 4) * 8;

    // staging geometry: 16B chunk c in [0,1024); row = c>>3, k8 = c&7.
    // wave handles chunk groups g = wave*4+q, chunks g*64+lane.
    const int srow = ((wave * 4) << 3) >> 3;  // placeholder; computed per q
    (void)srow;

    f32x4 acc[4][4];
    #pragma unroll
    for (int m = 0; m < 4; ++m)
        #pragma unroll
        for (int n = 0; n < 4; ++n)
            acc[m][n] = (f32x4){0.f, 0.f, 0.f, 0.f};

    auto stage = [&](int sel, int kc) {
        #pragma unroll
        for (int q = 0; q < 4; ++q) {
            const int g   = wave * 4 + q;
            const int c   = g * 64 + lane;
            const int row = c >> 3;
            const int k8  = c & 7;
            const unsigned short* ga = pb + (size_t)(i0 + row) * DD + kc + k8 * 8;
            const unsigned short* gb = pb + (size_t)(j0 + row) * DD + kc + k8 * 8;
            __builtin_amdgcn_global_load_lds(
                (const __attribute__((address_space(1))) unsigned int*)ga,
                (__attribute__((address_space(3))) unsigned int*)&As[sel][g * 512],
                16, 0, 0);
            __builtin_amdgcn_global_load_lds(
                (const __attribute__((address_space(1))) unsigned int*)gb,
                (__attribute__((address_space(3))) unsigned int*)&Bs[sel][g * 512],
                16, 0, 0);
        }
    };

    stage(0, 0);
    __syncthreads();          // drains vmcnt before barrier (compiler semantics)

    int sel = 0;
    for (int ks = 0; ks < 4; ++ks) {
        if (ks < 3) stage(sel ^ 1, (ks + 1) * 64);

        #pragma unroll
        for (int kq = 0; kq < 2; ++kq) {
            bf16x8 a[4], b[4];
            #pragma unroll
            for (int m = 0; m < 4; ++m)
                a[m] = *(const bf16x8*)&As[sel][(wm * 64 + m * 16 + lr) * 64 + kq * 32 + lk];
            #pragma unroll
            for (int n = 0; n < 4; ++n)
                b[n] = *(const bf16x8*)&Bs[sel][(wn * 64 + n * 16 + lr) * 64 + kq * 32 + lk];
            #pragma unroll
            for (int m = 0; m < 4; ++m)
                #pragma unroll
                for (int n = 0; n < 4; ++n)
                    acc[m][n] = __builtin_amdgcn_mfma_f32_16x16x32_bf16(
                        a[m], b[n], acc[m][n], 0, 0, 0);
        }
        __syncthreads();      // waits vmcnt(0)+lgkmcnt(0): staging done, reads done
        sel ^= 1;
    }

    // ---- hinge epilogue (fp32, in-register; no C write) ----
    const int cj = lane & 15;
    const int r0 = (lane >> 4) * 4;
    float lsum = 0.f;
    #pragma unroll
    for (int m = 0; m < 4; ++m) {
        const int ibase = i0 + wm * 64 + m * 16 + r0;
        float aiv[4];
        #pragma unroll
        for (int r = 0; r < 4; ++r) aiv[r] = ai[ibase + r];
        #pragma unroll
        for (int n = 0; n < 4; ++n) {
            const int j = j0 + wn * 64 + n * 16 + cj;
            const float nbj = nb[j];
            #pragma unroll
            for (int r = 0; r < 4; ++r) {
                const int i = ibase + r;
                float h = fmaf(2.f, acc[m][n][r], aiv[r] - nbj);
                h = fmaxf(h, 0.f);
                if (j != i && j != i + NN) lsum += h;
            }
        }
    }

    #pragma unroll
    for (int off = 32; off > 0; off >>= 1) lsum += __shfl_down(lsum, off);
    if (lane == 0) wsum[wave] = lsum;
    __syncthreads();
    if (t == 0)
        partial[blockIdx.y * gridDim.x + blockIdx.x] =
            wsum[0] + wsum[1] + wsum[2] + wsum[3];
}

// ---------------------------------------------------------------------------
// Kernel C: sum partials, scale, write scalar.
// ---------------------------------------------------------------------------
__global__ __launch_bounds__(256) void final_reduce(
    const float* __restrict__ partial, float* __restrict__ out,
    int n, float scale)
{
    const int t = threadIdx.x;
    float s = 0.f;
    for (int i = t; i < n; i += 256) s += partial[i];
    #pragma unroll
    for (int off = 32; off > 0; off >>= 1) s += __shfl_down(s, off);
    __shared__ float w[4];
    if ((t & 63) == 0) w[t >> 6] = s;
    __syncthreads();
    if (t == 0) out[0] = (w[0] + w[1] + w[2] + w[3]) * scale;
}

// ---------------------------------------------------------------------------
extern "C" void kernel_launch(void* const* d_in, const int* in_sizes, int n_in,
                              void* d_out, int out_size, void* d_ws, size_t ws_size,
                              hipStream_t stream) {
    const float* p1 = (const float*)d_in[0];
    const float* p2 = (const float*)d_in[1];
    float* out = (float*)d_out;

    char* ws = (char*)d_ws;
    unsigned short* pb = (unsigned short*)ws;                       // 4 MB (8192x256 bf16)
    float* nb      = (float*)(ws + (size_t)2 * NN * DD * 2);        // 32 KB
    float* ai      = nb + 2 * NN;                                   // 16 KB
    float* partial = ai + NN;                                       // 2048 f32

    stats_convert<<<NN / 4, 256, 0, stream>>>(p1, p2, pb, nb, ai);
    gemm_hinge<<<dim3(64, 32), 256, 0, stream>>>(pb, nb, ai, partial);
    const float scale = 1.0f / ((float)NN * (float)(NN - 1));
    final_reduce<<<1, 256, 0, stream>>>(partial, out, 64 * 32, scale);
}

// Round 4
// 39.404 us; speedup vs baseline: 6.5158x; 1.0824x over previous
//
#include <hip/hip_runtime.h>

#define NN 4096
#define DD 256
#define MARGIN 0.5f

typedef __attribute__((ext_vector_type(8))) short bf16x8;  // 8 bf16 (4 VGPRs)
typedef __attribute__((ext_vector_type(4))) float f32x4;   // MFMA C/D

__device__ inline unsigned short f32_to_bf16_rne(float v) {
    unsigned int b = __float_as_uint(v);
    b += 0x7FFFu + ((b >> 16) & 1u);   // round-to-nearest-even
    return (unsigned short)(b >> 16);
}

// ---------------------------------------------------------------------------
// Kernel A: per-row stats + bf16 convert into concatenated layout.
// pb rows [0,4096) = p1, rows [4096,8192) = p2.  nb[j] = ||row_j||^2 (fp32).
// ai[i] = ||p1_i - p2_i||^2 - ||p1_i||^2 + MARGIN   (exact fp32).
// ---------------------------------------------------------------------------
__global__ __launch_bounds__(256) void stats_convert(
    const float* __restrict__ p1, const float* __restrict__ p2,
    unsigned short* __restrict__ pb, float* __restrict__ nb,
    float* __restrict__ ai)
{
    const int wave = threadIdx.x >> 6;
    const int lane = threadIdx.x & 63;
    const int row  = blockIdx.x * 4 + wave;

    const float4 x = *(const float4*)&p1[(size_t)row * DD + lane * 4];
    const float4 y = *(const float4*)&p2[(size_t)row * DD + lane * 4];

    ushort4 xb, yb;
    xb.x = f32_to_bf16_rne(x.x); xb.y = f32_to_bf16_rne(x.y);
    xb.z = f32_to_bf16_rne(x.z); xb.w = f32_to_bf16_rne(x.w);
    yb.x = f32_to_bf16_rne(y.x); yb.y = f32_to_bf16_rne(y.y);
    yb.z = f32_to_bf16_rne(y.z); yb.w = f32_to_bf16_rne(y.w);
    *(ushort4*)&pb[(size_t)row * DD + lane * 4] = xb;
    *(ushort4*)&pb[(size_t)(NN + row) * DD + lane * 4] = yb;

    float s1 = x.x*x.x + x.y*x.y + x.z*x.z + x.w*x.w;
    float s2 = y.x*y.x + y.y*y.y + y.z*y.z + y.w*y.w;
    float dx = x.x-y.x, dy = x.y-y.y, dz = x.z-y.z, dw = x.w-y.w;
    float sa = dx*dx + dy*dy + dz*dz + dw*dw;

    #pragma unroll
    for (int off = 32; off > 0; off >>= 1) {
        s1 += __shfl_down(s1, off);
        s2 += __shfl_down(s2, off);
        sa += __shfl_down(sa, off);
    }
    if (lane == 0) {
        nb[row]      = s1;
        nb[NN + row] = s2;
        ai[row]      = sa - s1 + MARGIN;
    }
}

// ---------------------------------------------------------------------------
// Kernel B: register-resident-A GEMM + fused hinge.
// 256 blocks (1/CU), 512 thr = 8 waves (2M x 4N). Block owns a 128-row
// A-stripe (p1), held ENTIRELY in registers (per wave: 64 rows x 256 k =
// a[4][8] bf16x8 = 128 VGPRs), and loops over 8 j-tiles of 128 concat rows.
// B is double-buffered in LDS (2 x 64 KB, full K per stage) via
// global_load_lds width=16 with linear dest + inverse-XOR-swizzled global
// source; ds_read_b128 applies the same XOR (chunk ^= row&7) -> conflict-free
// (rule 21 / T2). One __syncthreads per j-tile.
// Epilogue (in-register): h = relu(2*dot + ai[i] - nb[j]), skip j==i, j==i+NN.
// ---------------------------------------------------------------------------
__global__ __launch_bounds__(512, 2) void gemm_hinge(
    const unsigned short* __restrict__ pb,
    const float* __restrict__ nb, const float* __restrict__ ai,
    float* __restrict__ partial)
{
    __shared__ unsigned short Bs[2][128 * 256];   // 2 x 64 KB
    __shared__ float wsum[8];

    const int t    = threadIdx.x;
    const int lane = t & 63;
    const int wave = t >> 6;       // 0..7
    const int wm   = wave >> 2;    // 0..1 (M)
    const int wn   = wave & 3;     // 0..3 (N)

    // XCD-bijective swizzle: bid = 64a + 8b + x -> XCD x gets istripes 4x..4x+3
    // (all 8 jgroups of a stripe on one XCD for A-panel L2 locality).
    const int bid     = blockIdx.x;
    const int istripe = (bid & 7) * 4 + (bid >> 6);
    const int jgroup  = (bid >> 3) & 7;
    const int i0      = istripe * 128;

    const int lr = lane & 15;      // A row / B col within 16
    const int l4 = lane >> 4;      // 0..3
    const int lk = l4 * 8;         // k offset of lane's 8 contiguous bf16

    // ---- A fragments in registers: rows i0 + wm*64 + m*16 + lr, full K ----
    bf16x8 a[4][8];
    #pragma unroll
    for (int m = 0; m < 4; ++m) {
        const unsigned short* ar = pb + (size_t)(i0 + wm * 64 + m * 16 + lr) * DD;
        #pragma unroll
        for (int kq = 0; kq < 8; ++kq)
            a[m][kq] = *(const bf16x8*)(ar + kq * 32 + lk);
    }

    // ---- ai preload (this lane's 16 fixed i-rows) ----
    const int r0 = l4 * 4;
    float aiv[4][4];
    #pragma unroll
    for (int m = 0; m < 4; ++m)
        #pragma unroll
        for (int r = 0; r < 4; ++r)
            aiv[m][r] = ai[i0 + wm * 64 + m * 16 + r0 + r];

    // ---- B staging: tile = 128 rows x 32 chunks of 16B. Linear LDS dest,
    //      global source pre-swizzled so swizzled reads land correctly. ----
    auto stage = [&](int sel, int jt) {
        const int j0 = jt * 128;
        #pragma unroll
        for (int q = 0; q < 8; ++q) {
            const int cbase = q * 512 + wave * 64;       // wave-uniform chunk base
            const int c     = cbase + lane;              // this lane's chunk
            const int row   = c >> 5;
            const int cw    = c & 31;
            const unsigned short* g =
                pb + (size_t)(j0 + row) * DD + ((cw ^ (row & 7)) * 8);
            __builtin_amdgcn_global_load_lds(
                (const __attribute__((address_space(1))) unsigned int*)g,
                (__attribute__((address_space(3))) unsigned int*)&Bs[sel][cbase * 8],
                16, 0, 0);
        }
    };

    const int jt0 = jgroup * 8;
    float lsum = 0.f;

    stage(0, jt0);
    __syncthreads();

    int sel = 0;
    for (int jj = 0; jj < 8; ++jj) {
        const int jt = jt0 + jj;
        const int j0 = jt * 128;
        if (jj < 7) stage(sel ^ 1, jt + 1);

        f32x4 acc[4][2];
        #pragma unroll
        for (int m = 0; m < 4; ++m)
            #pragma unroll
            for (int n = 0; n < 2; ++n)
                acc[m][n] = (f32x4){0.f, 0.f, 0.f, 0.f};

        #pragma unroll
        for (int kq = 0; kq < 8; ++kq) {
            bf16x8 b[2];
            #pragma unroll
            for (int n = 0; n < 2; ++n) {
                const int row = wn * 32 + n * 16 + lr;
                const int cl  = kq * 4 + l4;
                b[n] = *(const bf16x8*)&Bs[sel][row * 256 + ((cl ^ (row & 7)) * 8)];
            }
            #pragma unroll
            for (int m = 0; m < 4; ++m)
                #pragma unroll
                for (int n = 0; n < 2; ++n)
                    acc[m][n] = __builtin_amdgcn_mfma_f32_16x16x32_bf16(
                        a[m][kq], b[n], acc[m][n], 0, 0, 0);
        }

        // ---- hinge epilogue for this j-tile (registers only) ----
        #pragma unroll
        for (int n = 0; n < 2; ++n) {
            const int j   = j0 + wn * 32 + n * 16 + lr;
            const float nbj = nb[j];
            #pragma unroll
            for (int m = 0; m < 4; ++m) {
                #pragma unroll
                for (int r = 0; r < 4; ++r) {
                    const int i = i0 + wm * 64 + m * 16 + r0 + r;
                    float h = fmaf(2.f, acc[m][n][r], aiv[m][r] - nbj);
                    h = fmaxf(h, 0.f);
                    if (j != i && j != i + NN) lsum += h;
                }
            }
        }

        __syncthreads();   // drains stage(jt+1) vmcnt + all Bs reads; swap safe
        sel ^= 1;
    }

    // ---- block reduction (deterministic) ----
    #pragma unroll
    for (int off = 32; off > 0; off >>= 1) lsum += __shfl_down(lsum, off);
    if (lane == 0) wsum[wave] = lsum;
    __syncthreads();
    if (t == 0) {
        float s = 0.f;
        #pragma unroll
        for (int w = 0; w < 8; ++w) s += wsum[w];
        partial[bid] = s;
    }
}

// ---------------------------------------------------------------------------
// Kernel C: sum partials, scale, write scalar.
// ---------------------------------------------------------------------------
__global__ __launch_bounds__(256) void final_reduce(
    const float* __restrict__ partial, float* __restrict__ out,
    int n, float scale)
{
    const int t = threadIdx.x;
    float s = 0.f;
    for (int i = t; i < n; i += 256) s += partial[i];
    #pragma unroll
    for (int off = 32; off > 0; off >>= 1) s += __shfl_down(s, off);
    __shared__ float w[4];
    if ((t & 63) == 0) w[t >> 6] = s;
    __syncthreads();
    if (t == 0) out[0] = (w[0] + w[1] + w[2] + w[3]) * scale;
}

// ---------------------------------------------------------------------------
extern "C" void kernel_launch(void* const* d_in, const int* in_sizes, int n_in,
                              void* d_out, int out_size, void* d_ws, size_t ws_size,
                              hipStream_t stream) {
    const float* p1 = (const float*)d_in[0];
    const float* p2 = (const float*)d_in[1];
    float* out = (float*)d_out;

    char* ws = (char*)d_ws;
    unsigned short* pb = (unsigned short*)ws;                       // 4 MB (8192x256 bf16)
    float* nb      = (float*)(ws + (size_t)2 * NN * DD * 2);        // 32 KB
    float* ai      = nb + 2 * NN;                                   // 16 KB
    float* partial = ai + NN;                                       // 256 f32

    stats_convert<<<NN / 4, 256, 0, stream>>>(p1, p2, pb, nb, ai);
    gemm_hinge<<<256, 512, 0, stream>>>(pb, nb, ai, partial);
    const float scale = 1.0f / ((float)NN * (float)(NN - 1));
    final_reduce<<<1, 256, 0, stream>>>(partial, out, 256, scale);
}

// Round 5
// 36.415 us; speedup vs baseline: 7.0507x; 1.0821x over previous
//
#include <hip/hip_runtime.h>

#define NN 4096
#define DD 256
#define MARGIN 0.5f

typedef __attribute__((ext_vector_type(8))) short bf16x8;  // 8 bf16 (4 VGPRs)
typedef __attribute__((ext_vector_type(4))) float f32x4;   // MFMA C/D

__device__ inline unsigned short f32_to_bf16_rne(float v) {
    unsigned int b = __float_as_uint(v);
    b += 0x7FFFu + ((b >> 16) & 1u);   // round-to-nearest-even
    return (unsigned short)(b >> 16);
}

// ---------------------------------------------------------------------------
// Kernel A: per-row stats + bf16 convert into concatenated layout.
// pb rows [0,4096) = p1, rows [4096,8192) = p2.  nb[j] = ||row_j||^2 (fp32).
// ai[i] = ||p1_i - p2_i||^2 - ||p1_i||^2 + MARGIN   (exact fp32).
// ---------------------------------------------------------------------------
__global__ __launch_bounds__(256) void stats_convert(
    const float* __restrict__ p1, const float* __restrict__ p2,
    unsigned short* __restrict__ pb, float* __restrict__ nb,
    float* __restrict__ ai)
{
    const int wave = threadIdx.x >> 6;
    const int lane = threadIdx.x & 63;
    const int row  = blockIdx.x * 4 + wave;

    const float4 x = *(const float4*)&p1[(size_t)row * DD + lane * 4];
    const float4 y = *(const float4*)&p2[(size_t)row * DD + lane * 4];

    ushort4 xb, yb;
    xb.x = f32_to_bf16_rne(x.x); xb.y = f32_to_bf16_rne(x.y);
    xb.z = f32_to_bf16_rne(x.z); xb.w = f32_to_bf16_rne(x.w);
    yb.x = f32_to_bf16_rne(y.x); yb.y = f32_to_bf16_rne(y.y);
    yb.z = f32_to_bf16_rne(y.z); yb.w = f32_to_bf16_rne(y.w);
    *(ushort4*)&pb[(size_t)row * DD + lane * 4] = xb;
    *(ushort4*)&pb[(size_t)(NN + row) * DD + lane * 4] = yb;

    float s1 = x.x*x.x + x.y*x.y + x.z*x.z + x.w*x.w;
    float s2 = y.x*y.x + y.y*y.y + y.z*y.z + y.w*y.w;
    float dx = x.x-y.x, dy = x.y-y.y, dz = x.z-y.z, dw = x.w-y.w;
    float sa = dx*dx + dy*dy + dz*dz + dw*dw;

    #pragma unroll
    for (int off = 32; off > 0; off >>= 1) {
        s1 += __shfl_down(s1, off);
        s2 += __shfl_down(s2, off);
        sa += __shfl_down(sa, off);
    }
    if (lane == 0) {
        nb[row]      = s1;
        nb[NN + row] = s2;
        ai[row]      = sa - s1 + MARGIN;
    }
}

// ---------------------------------------------------------------------------
// Kernel B: register-resident-A GEMM + fused hinge, 2 blocks/CU.
// 512 blocks x 256 thr (4 waves, 2M x 2N). Block owns a 128-row A-stripe
// (p1) held in registers (per wave: 64 rows x 256 k = a[4][8] bf16x8 = 128
// VGPRs) and loops over 8 j-tiles of 64 concat rows (one jgroup = 512 cols).
// B double-buffered in LDS (2 x 32 KB, full K per stage) via global_load_lds
// width=16: linear LDS dest + inverse-XOR-swizzled global source, XOR on
// ds_read (chunk ^= row&7) -> bank-balanced (8 words/bank = LDS minimum).
// 64 KB LDS/block + <=256 VGPR -> 2 blocks/CU; co-resident block hides the
// barrier vmcnt-drain + epilogue of the other (m114 implicit overlap).
// Epilogue: h = relu(2*dot + ai[i] - nb[j]), skip j==i and j==i+NN.
// ---------------------------------------------------------------------------
__global__ __launch_bounds__(256, 2) void gemm_hinge(
    const unsigned short* __restrict__ pb,
    const float* __restrict__ nb, const float* __restrict__ ai,
    float* __restrict__ partial)
{
    __shared__ unsigned short Bs[2][64 * 256];   // 2 x 32 KB
    __shared__ float wsum[4];

    const int t    = threadIdx.x;
    const int lane = t & 63;
    const int wave = t >> 6;       // 0..3
    const int wm   = wave >> 1;    // 0..1 (M)
    const int wn   = wave & 1;     // 0..1 (N)

    // XCD-bijective swizzle (512 = 8 XCD x 64): XCD x owns istripes 4x..4x+3,
    // all 16 jgroups of a stripe land on one XCD (A-panel + B L2 locality).
    const int bid     = blockIdx.x;
    const int istripe = (bid & 7) * 4 + (bid >> 7);   // 0..31
    const int jgroup  = (bid >> 3) & 15;              // 0..15
    const int i0      = istripe * 128;

    const int lr = lane & 15;      // A row / B col within 16
    const int l4 = lane >> 4;      // 0..3
    const int lk = l4 * 8;         // k offset of lane's 8 contiguous bf16

    // ---- A fragments in registers: rows i0 + wm*64 + m*16 + lr, full K ----
    bf16x8 a[4][8];
    #pragma unroll
    for (int m = 0; m < 4; ++m) {
        const unsigned short* ar = pb + (size_t)(i0 + wm * 64 + m * 16 + lr) * DD;
        #pragma unroll
        for (int kq = 0; kq < 8; ++kq)
            a[m][kq] = *(const bf16x8*)(ar + kq * 32 + lk);
    }

    // ---- ai preload (this lane's 16 fixed i-rows) ----
    const int r0 = l4 * 4;
    float aiv[4][4];
    #pragma unroll
    for (int m = 0; m < 4; ++m)
        #pragma unroll
        for (int r = 0; r < 4; ++r)
            aiv[m][r] = ai[i0 + wm * 64 + m * 16 + r0 + r];

    // ---- B staging: tile = 64 rows x 32 chunks of 16B = 2048 chunks.
    //      Thread t stages chunks c = q*256 + t (q=0..7); LDS dest linear,
    //      global source chunk = cw ^ (row&7)  (rule 21 both-sides swizzle).
    auto stage = [&](int sel, int jt) {
        const unsigned short* base = pb + (size_t)jt * 64 * DD;
        #pragma unroll
        for (int q = 0; q < 8; ++q) {
            const int c   = q * 256 + t;
            const int row = c >> 5;
            const int cw  = c & 31;
            const unsigned short* g = base + row * DD + ((cw ^ (row & 7)) * 8);
            __builtin_amdgcn_global_load_lds(
                (const __attribute__((address_space(1))) unsigned int*)g,
                (__attribute__((address_space(3))) unsigned int*)
                    &Bs[sel][(q * 256 + wave * 64) * 8],
                16, 0, 0);
        }
    };

    const int jt0 = jgroup * 8;
    float lsum = 0.f;

    stage(0, jt0);
    __syncthreads();

    int sel = 0;
    for (int jj = 0; jj < 8; ++jj) {
        const int j0 = (jt0 + jj) * 64;
        if (jj < 7) stage(sel ^ 1, jt0 + jj + 1);

        f32x4 acc[4][2];
        #pragma unroll
        for (int m = 0; m < 4; ++m)
            #pragma unroll
            for (int n = 0; n < 2; ++n)
                acc[m][n] = (f32x4){0.f, 0.f, 0.f, 0.f};

        #pragma unroll
        for (int kq = 0; kq < 8; ++kq) {
            bf16x8 b[2];
            #pragma unroll
            for (int n = 0; n < 2; ++n) {
                const int row = wn * 32 + n * 16 + lr;
                const int cl  = kq * 4 + l4;
                b[n] = *(const bf16x8*)&Bs[sel][row * 256 + ((cl ^ (row & 7)) * 8)];
            }
            #pragma unroll
            for (int m = 0; m < 4; ++m)
                #pragma unroll
                for (int n = 0; n < 2; ++n)
                    acc[m][n] = __builtin_amdgcn_mfma_f32_16x16x32_bf16(
                        a[m][kq], b[n], acc[m][n], 0, 0, 0);
        }

        // ---- hinge epilogue for this j-tile (registers only) ----
        #pragma unroll
        for (int n = 0; n < 2; ++n) {
            const int j     = j0 + wn * 32 + n * 16 + lr;
            const float nbj = nb[j];
            #pragma unroll
            for (int m = 0; m < 4; ++m) {
                #pragma unroll
                for (int r = 0; r < 4; ++r) {
                    const int i = i0 + wm * 64 + m * 16 + r0 + r;
                    float h = fmaf(2.f, acc[m][n][r], aiv[m][r] - nbj);
                    h = fmaxf(h, 0.f);
                    if (j != i && j != i + NN) lsum += h;
                }
            }
        }

        __syncthreads();   // drains stage(jt+1) + all Bs reads; swap safe
        sel ^= 1;
    }

    // ---- block reduction (deterministic) ----
    #pragma unroll
    for (int off = 32; off > 0; off >>= 1) lsum += __shfl_down(lsum, off);
    if (lane == 0) wsum[wave] = lsum;
    __syncthreads();
    if (t == 0)
        partial[bid] = wsum[0] + wsum[1] + wsum[2] + wsum[3];
}

// ---------------------------------------------------------------------------
// Kernel C: sum partials, scale, write scalar.
// ---------------------------------------------------------------------------
__global__ __launch_bounds__(256) void final_reduce(
    const float* __restrict__ partial, float* __restrict__ out,
    int n, float scale)
{
    const int t = threadIdx.x;
    float s = 0.f;
    for (int i = t; i < n; i += 256) s += partial[i];
    #pragma unroll
    for (int off = 32; off > 0; off >>= 1) s += __shfl_down(s, off);
    __shared__ float w[4];
    if ((t & 63) == 0) w[t >> 6] = s;
    __syncthreads();
    if (t == 0) out[0] = (w[0] + w[1] + w[2] + w[3]) * scale;
}

// ---------------------------------------------------------------------------
extern "C" void kernel_launch(void* const* d_in, const int* in_sizes, int n_in,
                              void* d_out, int out_size, void* d_ws, size_t ws_size,
                              hipStream_t stream) {
    const float* p1 = (const float*)d_in[0];
    const float* p2 = (const float*)d_in[1];
    float* out = (float*)d_out;

    char* ws = (char*)d_ws;
    unsigned short* pb = (unsigned short*)ws;                       // 4 MB (8192x256 bf16)
    float* nb      = (float*)(ws + (size_t)2 * NN * DD * 2);        // 32 KB
    float* ai      = nb + 2 * NN;                                   // 16 KB
    float* partial = ai + NN;                                       // 512 f32

    stats_convert<<<NN / 4, 256, 0, stream>>>(p1, p2, pb, nb, ai);
    gemm_hinge<<<512, 256, 0, stream>>>(pb, nb, ai, partial);
    const float scale = 1.0f / ((float)NN * (float)(NN - 1));
    final_reduce<<<1, 256, 0, stream>>>(partial, out, 512, scale);
}